// Round 1
// 2278.856 us; speedup vs baseline: 1.0260x; 1.0260x over previous
//
#include <hip/hip_runtime.h>
#include <stdint.h>

typedef unsigned short u16;
typedef unsigned int u32;
typedef unsigned long long u64;

#define B_ 64
#define T_ 512
#define N_ 128
#define H_ 512
#define KDIM 640        // H + N
#define FL 32           // u32 per 128B line
// sync lines: [0..7] org counters (agent) | [8+xcc] flag line: flag[s] = t+1 once
// block s of XCD xcc has drained h_{t+1} to its L2 (32 dwords = one 128B line).

typedef __attribute__((ext_vector_type(8))) short short8;
typedef __attribute__((ext_vector_type(4))) float floatx4;

__device__ __forceinline__ float sigf(float x) { return 1.0f / (1.0f + __expf(-x)); }
__device__ __forceinline__ float tanh_(float x) { return 1.0f - 2.0f / (1.0f + __expf(2.0f * x)); }

__device__ __forceinline__ u16 f2bf(float x) {
    u32 u = __float_as_uint(x);
    u32 r = (u + 0x7FFFu + ((u >> 16) & 1u)) >> 16;   // RNE
    return (u16)r;
}

// ILP-4 heater: 32 FMA issue slots at ~full issue rate (4 independent chains).
// R10's dependent-chain heater only reached 25% issue duty -> VALUBusy 16% and
// the SMU kept the engine near idle clock (~700 MHz inferred from MfmaUtil).
__device__ __forceinline__ void heat4(float* h) {
#pragma unroll
    for (int i = 0; i < 8; ++i) {
        h[0] = __builtin_fmaf(h[0], 1.0000001f, 1e-30f);
        h[1] = __builtin_fmaf(h[1], 1.0000001f, 1e-30f);
        h[2] = __builtin_fmaf(h[2], 1.0000001f, 1e-30f);
        h[3] = __builtin_fmaf(h[3], 1.0000001f, 1e-30f);
    }
    asm volatile("" : "+v"(h[0]), "+v"(h[1]), "+v"(h[2]), "+v"(h[3]));
}

// X [B,T,N] fp32 -> Xb [T,B,N] bf16
__global__ __launch_bounds__(256) void k_xb(const float* __restrict__ X, u16* __restrict__ Xb) {
    int i = blockIdx.x * 256 + threadIdx.x;
    int n = i & 127, b = (i >> 7) & 63, t = i >> 13;
    Xb[i] = f2bf(X[(b * T_ + t) * N_ + n]);
}

// Wcat^T [2048 cols][640 k] bf16: rows k<512 from Wh, k>=512 from Wx
__global__ __launch_bounds__(256) void k_wcat(const float* __restrict__ Wx, const float* __restrict__ Wh,
                                              u16* __restrict__ Wt) {
    int i = blockIdx.x * 256 + threadIdx.x;
    int c = i & 2047, k = i >> 11;
    float v = (k < H_) ? Wh[k * 2048 + c] : Wx[(k - H_) * 2048 + c];
    Wt[c * KDIM + k] = f2bf(v);
}

// Batch-per-XCD LSTM. R11: single-layer flag barrier (plain stores + coalesced
// agent-load polling of one 128B line per XCD) replaces the 3-layer
// counter-RMW -> poller -> mailbox-RMW chain; ILP-4 heater; x-part MFMAs
// hoisted ahead of the wait with 1-step x prefetch.
__global__ __launch_bounds__(256, 1) void k_lstm(const u16* __restrict__ Wt, const u16* __restrict__ Xb,
                                                 u16* __restrict__ hs, const float* __restrict__ bias,
                                                 u32* __restrict__ sync) {
    __shared__ float sG[4 * 136];      // per-wave 8 rows x 16 cols (pitch 17)
    __shared__ int sSlot, sXcc, sEpoch;

    const int tid = threadIdx.x;
    const int lane = tid & 63, wv = tid >> 6;
    const int l16 = lane & 15, quad = lane >> 4;

    // ---- one-time: XCD self-organization (R7/R8-proven; sleep OK here) ----
    if (tid == 0) {
        u32 xcc;
        asm volatile("s_getreg_b32 %0, hwreg(HW_REG_XCC_ID)" : "=s"(xcc));
        xcc &= 7;
        u32 slot = __hip_atomic_fetch_add(sync + xcc * FL, 1u, __ATOMIC_RELAXED, __HIP_MEMORY_SCOPE_AGENT);
        int ok = -1;
        if (slot < 32) {
            int g = 0;
            while (__hip_atomic_load(sync + xcc * FL, __ATOMIC_RELAXED, __HIP_MEMORY_SCOPE_AGENT) < 32u) {
                __builtin_amdgcn_s_sleep(8);
                if (++g > 2000000) { ok = -2; break; }
            }
            if (ok == -1) ok = (int)slot;
        }
        sSlot = ok; sXcc = (int)xcc; sEpoch = 0;
    }
    __syncthreads();
    const int s = sSlot;
    if (s < 0) return;
    const int xcc = sXcc;
    const int b0 = 8 * xcc;

    // gate biases for gate-math lane (lane<16 -> batch lane>>1, cols j0=(lane&1)*2, j0+1)
    float biA, bjA, bfA, boA, biB, bjB, bfB, boB;
    {
        int j0 = (lane & 1) * 2;
        int hcA = s * 16 + wv * 4 + j0, hcB = hcA + 1;
        biA = bias[hcA]; bjA = bias[512 + hcA]; bfA = bias[1024 + hcA] + 1.0f; boA = bias[1536 + hcA];
        biB = bias[hcB]; bjB = bias[512 + hcB]; bfB = bias[1024 + hcB] + 1.0f; boB = bias[1536 + hcB];
    }

    // weight fragments: local col c=l16 -> global col (c>>2)*512 + s*16 + wv*4 + (c&3)
    short8 bfr[20];
    {
        size_t bcol = (size_t)(l16 >> 2) * 512 + s * 16 + wv * 4 + (l16 & 3);
        const u16* wp = Wt + bcol * KDIM + quad * 8;
#pragma unroll
        for (int ks = 0; ks < 20; ++ks) bfr[ks] = *(const short8*)(wp + ks * 32);
    }

    u32* flags = sync + (size_t)(8 + xcc) * FL;
    const int bA = l16 & 7;
    float cstA = 0.f, cstB = 0.f;
    float hh[4] = {1.f, 1.f, 1.f, 1.f};
    __syncthreads();

    // x fragments for t=0 (recurrence-independent; 1-step prefetch thereafter)
    short8 xcur[4], xnxt[4];
    {
        const u16* xrow = Xb + ((size_t)b0 + bA) * N_ + quad * 8;
#pragma unroll
        for (int ks = 0; ks < 4; ++ks) xcur[ks] = *(const short8*)(xrow + ks * 32);
    }

    for (int t = 0; t < T_; ++t) {
        floatx4 p = {0.f, 0.f, 0.f, 0.f}, q = {0.f, 0.f, 0.f, 0.f};

        // x contribution first: independent of h_t, overlaps the barrier wait
        p = __builtin_amdgcn_mfma_f32_16x16x32_bf16(xcur[0], bfr[16], p, 0, 0, 0);
        q = __builtin_amdgcn_mfma_f32_16x16x32_bf16(xcur[1], bfr[17], q, 0, 0, 0);
        p = __builtin_amdgcn_mfma_f32_16x16x32_bf16(xcur[2], bfr[18], p, 0, 0, 0);
        q = __builtin_amdgcn_mfma_f32_16x16x32_bf16(xcur[3], bfr[19], q, 0, 0, 0);

        if (t > 0) {
            if (wv == 0) {
                // lanes 0-31: one coalesced 128B agent-load per poll round.
                // Loads don't serialize at L2 the way RMWs do -> no mailbox
                // fan-out layer needed.
                bool done = (lane >= 32);
                u32* fp = flags + lane;
                int g = 0;
                while (!__all(done)) {
                    if (!done)
                        done = (__hip_atomic_load(fp, __ATOMIC_RELAXED, __HIP_MEMORY_SCOPE_AGENT) >= (u32)t);
                    heat4(hh);
                    if (++g > 1000000) break;   // fail-safe
                }
                if (lane == 0)
                    __hip_atomic_store(&sEpoch, t, __ATOMIC_RELAXED, __HIP_MEMORY_SCOPE_WORKGROUP);
            } else {
                // waves 1-3: hot LDS spin, double heater for issue density
                int g = 0;
                while (__hip_atomic_load(&sEpoch, __ATOMIC_RELAXED, __HIP_MEMORY_SCOPE_WORKGROUP) < t) {
                    heat4(hh);
                    heat4(hh);
                    if (++g > 3000000) break;   // fail-safe
                }
            }
            asm volatile("" ::: "memory");
        }

        // h fragments from this XCD's L2 (fresh addresses each t; R7/R8-proven)
        short8 afr[16];
        const u16* hrow = hs + ((size_t)t * 64 + b0 + bA) * H_ + quad * 8;
#pragma unroll
        for (int ks = 0; ks < 16; ++ks) afr[ks] = *(const short8*)(hrow + ks * 32);

        // prefetch next x fragments (latency hides under h-MFMA + gate math)
        if (t + 1 < T_) {
            const u16* xrow = Xb + ((size_t)(t + 1) * 64 + b0 + bA) * N_ + quad * 8;
#pragma unroll
            for (int ks = 0; ks < 4; ++ks) xnxt[ks] = *(const short8*)(xrow + ks * 32);
        }

        // GEMM: M=16 (8 real batches dup), one N-tile (16 gate-cols), K=512 (h part)
#pragma unroll
        for (int ks = 0; ks < 16; ks += 2) {
            p = __builtin_amdgcn_mfma_f32_16x16x32_bf16(afr[ks],     bfr[ks],     p, 0, 0, 0);
            q = __builtin_amdgcn_mfma_f32_16x16x32_bf16(afr[ks + 1], bfr[ks + 1], q, 0, 0, 0);
        }
        floatx4 acc = p + q;

        // C/D: row = quad*4+r (rows 0..7 real), col = l16 -> wave-private sG
        if (quad < 2) {
            float* gb = sG + wv * 136 + (quad * 4) * 17 + l16;
#pragma unroll
            for (int r = 0; r < 4; ++r) gb[r * 17] = acc[r];
        }
        asm volatile("s_waitcnt lgkmcnt(0)" ::: "memory");

        // gate math (wave-private): lane<16 -> batch b=lane>>1, cols j0, j0+1
        if (lane < 16) {
            int b = lane >> 1, j0 = (lane & 1) * 2;
            const float* gr = sG + wv * 136 + b * 17;
            float giA = gr[j0]      + biA, giB = gr[j0 + 1]      + biB;
            float gjA = gr[4 + j0]  + bjA, gjB = gr[4 + j0 + 1]  + bjB;
            float gfA = gr[8 + j0]  + bfA, gfB = gr[8 + j0 + 1]  + bfB;
            float goA = gr[12 + j0] + boA, goB = gr[12 + j0 + 1] + boB;
            cstA = sigf(gfA) * cstA + sigf(giA) * tanh_(gjA);
            cstB = sigf(gfB) * cstB + sigf(giB) * tanh_(gjB);
            float hA = sigf(goA) * tanh_(cstA);
            float hB = sigf(goB) * tanh_(cstB);
            u32 pk = ((u32)f2bf(hB) << 16) | (u32)f2bf(hA);
            *(u32*)(hs + ((size_t)(t + 1) * 64 + b0 + b) * H_ + s * 16 + wv * 4 + j0) = pk;
        }

        // drain h to this XCD's L2, join 4 waves, publish one flag dword
        asm volatile("s_waitcnt vmcnt(0)" ::: "memory");
        __syncthreads();
        if (tid == 0)
            __hip_atomic_store(flags + s, (u32)(t + 1), __ATOMIC_RELAXED, __HIP_MEMORY_SCOPE_AGENT);

#pragma unroll
        for (int ks = 0; ks < 4; ++ks) xcur[ks] = xnxt[ks];
    }
    (void)hh;
}

// decoder + loss: rows R = t*64+b of hs[1..512]; 32 rows/block staged in LDS
__global__ __launch_bounds__(256) void k_dec(const u16* __restrict__ hs, const float* __restrict__ Wd,
                                             const float* __restrict__ bd, const float* __restrict__ Y,
                                             float* __restrict__ out) {
    __shared__ u16 sH[32 * H_];
    __shared__ float red[4];
    int tid = threadIdx.x;
    int R0 = blockIdx.x * 32;
    for (int u = tid; u < 2048; u += 256) {
        int row = u >> 6, ch = u & 63;
        *(short8*)(sH + row * H_ + ch * 8) =
            *(const short8*)(hs + (size_t)(64 + R0 + row) * H_ + ch * 8);
    }
    __syncthreads();

    int n = tid & 127, half = tid >> 7;
    float bdv = bd[n];
    float acc[16];
#pragma unroll
    for (int i = 0; i < 16; ++i) acc[i] = 0.f;

    for (int ko = 0; ko < H_ / 8; ++ko) {
        float wv[8];
#pragma unroll
        for (int j = 0; j < 8; ++j) wv[j] = Wd[(ko * 8 + j) * N_ + n];
#pragma unroll
        for (int i = 0; i < 16; ++i) {
            int r = half * 16 + i;
            const uint4 hv = *(const uint4*)(sH + r * H_ + ko * 8);
            acc[i] += __uint_as_float(hv.x << 16) * wv[0] + __uint_as_float(hv.x & 0xFFFF0000u) * wv[1]
                    + __uint_as_float(hv.y << 16) * wv[2] + __uint_as_float(hv.y & 0xFFFF0000u) * wv[3]
                    + __uint_as_float(hv.z << 16) * wv[4] + __uint_as_float(hv.z & 0xFFFF0000u) * wv[5]
                    + __uint_as_float(hv.w << 16) * wv[6] + __uint_as_float(hv.w & 0xFFFF0000u) * wv[7];
        }
    }
    float sse = 0.f;
#pragma unroll
    for (int i = 0; i < 16; ++i) {
        int R = R0 + half * 16 + i;
        int t = R >> 6, b = R & 63;
        float logit = sigf(acc[i] + bdv);
        float d = Y[(size_t)(b * T_ + t) * N_ + n] - logit;
        sse += d * d;
    }
    for (int off = 32; off > 0; off >>= 1) sse += __shfl_down(sse, off, 64);
    if ((tid & 63) == 0) red[tid >> 6] = sse;
    __syncthreads();
    if (tid == 0) {
        float tot = red[0] + red[1] + red[2] + red[3];
        atomicAdd(out, tot * (100.0f / 4194304.0f));
    }
}

extern "C" void kernel_launch(void* const* d_in, const int* in_sizes, int n_in,
                              void* d_out, int out_size, void* d_ws, size_t ws_size,
                              hipStream_t stream) {
    (void)in_sizes; (void)n_in; (void)out_size;
    const float* X  = (const float*)d_in[0];
    const float* Y  = (const float*)d_in[1];
    const float* Wx = (const float*)d_in[2];
    const float* Wh = (const float*)d_in[3];
    const float* bb = (const float*)d_in[4];
    const float* Wd = (const float*)d_in[5];
    const float* bd = (const float*)d_in[6];

    char* ws = (char*)d_ws;
    u32* syncz = (u32*)ws;
    const size_t sync_bytes = 131072;
    u16* hs  = (u16*)(ws + sync_bytes);
    const size_t hs_bytes = (size_t)(T_ + 1) * 64 * H_ * 2;   // 33,619,968
    u16* Xb  = (u16*)(ws + sync_bytes + hs_bytes);
    const size_t xb_bytes = (size_t)T_ * 64 * N_ * 2;         // 8,388,608
    u16* Wt  = (u16*)(ws + sync_bytes + hs_bytes + xb_bytes);
    const size_t need = sync_bytes + hs_bytes + xb_bytes + (size_t)2048 * KDIM * 2;
    if (ws_size < need) return;   // ~44.8 MB scratch required

    (void)hipMemsetAsync(syncz, 0, 65536, stream);            // org counters + flag lines
    (void)hipMemsetAsync(hs, 0, 64 * H_ * 2, stream);         // h_{-1} = 0
    (void)hipMemsetAsync(d_out, 0, sizeof(float), stream);

    k_xb<<<dim3((B_ * T_ * N_) / 256), dim3(256), 0, stream>>>(X, Xb);
    k_wcat<<<dim3((2048 * KDIM) / 256), dim3(256), 0, stream>>>(Wx, Wh, Wt);

    void* args[] = { (void*)&Wt, (void*)&Xb, (void*)&hs, (void*)&bb, (void*)&syncz };
    (void)hipLaunchCooperativeKernel((const void*)k_lstm, dim3(256), dim3(256), args, 0, stream);

    k_dec<<<dim3((B_ * T_) / 32), dim3(256), 0, stream>>>(hs, Wd, bd, Y, (float*)d_out);
}

// Round 2
// 2189.486 us; speedup vs baseline: 1.0679x; 1.0408x over previous
//
#include <hip/hip_runtime.h>
#include <stdint.h>

typedef unsigned short u16;
typedef unsigned int u32;
typedef unsigned long long u64;

#define B_ 64
#define T_ 512
#define N_ 128
#define H_ 512
#define KDIM 640        // H + N
#define FL 32           // u32 per 128B line
// sync lines: [0..7] org counters (agent) only. No per-step flags anymore:
// consumers poll hs data directly against the bf16-NaN sentinel 0x7FC0.

typedef __attribute__((ext_vector_type(8))) short short8;
typedef __attribute__((ext_vector_type(4))) float floatx4;

__device__ __forceinline__ float sigf(float x) { return 1.0f / (1.0f + __expf(-x)); }
__device__ __forceinline__ float tanh_(float x) { return 1.0f - 2.0f / (1.0f + __expf(2.0f * x)); }

__device__ __forceinline__ u16 f2bf(float x) {
    u32 u = __float_as_uint(x);
    u32 r = (u + 0x7FFFu + ((u >> 16) & 1u)) >> 16;   // RNE
    return (u16)r;
}

// X [B,T,N] fp32 -> Xb [T,B,N] bf16
__global__ __launch_bounds__(256) void k_xb(const float* __restrict__ X, u16* __restrict__ Xb) {
    int i = blockIdx.x * 256 + threadIdx.x;
    int n = i & 127, b = (i >> 7) & 63, t = i >> 13;
    Xb[i] = f2bf(X[(b * T_ + t) * N_ + n]);
}

// Wcat^T [2048 cols][640 k] bf16: rows k<512 from Wh, k>=512 from Wx
__global__ __launch_bounds__(256) void k_wcat(const float* __restrict__ Wx, const float* __restrict__ Wh,
                                              u16* __restrict__ Wt) {
    int i = blockIdx.x * 256 + threadIdx.x;
    int c = i & 2047, k = i >> 11;
    float v = (k < H_) ? Wh[k * 2048 + c] : Wx[(k - H_) * 2048 + c];
    Wt[c * KDIM + k] = f2bf(v);
}

// NaN-prefill hs rows [64, 513*64): 0x7FC0 bf16 sentinel. |h|<1 strictly, so
// f2bf can never produce this pattern -> unambiguous "not yet written".
__global__ __launch_bounds__(256) void k_fill(uint4* __restrict__ p) {
    int i = blockIdx.x * 256 + threadIdx.x;
    uint4 v; v.x = v.y = v.z = v.w = 0x7FC07FC0u;
    p[i] = v;
}

// 16 L1-bypass dwordx4 loads + drain, all in ONE asm block so the waitcnt
// cannot be separated from the loads (rule-18-safe: MFMAs depend on outputs).
#define PLOADS(SC) \
    asm volatile( \
        "global_load_dwordx4 %0, %16, off " SC "\n\t" \
        "global_load_dwordx4 %1, %16, off offset:64 " SC "\n\t" \
        "global_load_dwordx4 %2, %16, off offset:128 " SC "\n\t" \
        "global_load_dwordx4 %3, %16, off offset:192 " SC "\n\t" \
        "global_load_dwordx4 %4, %16, off offset:256 " SC "\n\t" \
        "global_load_dwordx4 %5, %16, off offset:320 " SC "\n\t" \
        "global_load_dwordx4 %6, %16, off offset:384 " SC "\n\t" \
        "global_load_dwordx4 %7, %16, off offset:448 " SC "\n\t" \
        "global_load_dwordx4 %8, %16, off offset:512 " SC "\n\t" \
        "global_load_dwordx4 %9, %16, off offset:576 " SC "\n\t" \
        "global_load_dwordx4 %10, %16, off offset:640 " SC "\n\t" \
        "global_load_dwordx4 %11, %16, off offset:704 " SC "\n\t" \
        "global_load_dwordx4 %12, %16, off offset:768 " SC "\n\t" \
        "global_load_dwordx4 %13, %16, off offset:832 " SC "\n\t" \
        "global_load_dwordx4 %14, %16, off offset:896 " SC "\n\t" \
        "global_load_dwordx4 %15, %16, off offset:960 " SC "\n\t" \
        "s_waitcnt vmcnt(0)" \
        : "=&v"(afr[0]), "=&v"(afr[1]), "=&v"(afr[2]), "=&v"(afr[3]), \
          "=&v"(afr[4]), "=&v"(afr[5]), "=&v"(afr[6]), "=&v"(afr[7]), \
          "=&v"(afr[8]), "=&v"(afr[9]), "=&v"(afr[10]), "=&v"(afr[11]), \
          "=&v"(afr[12]), "=&v"(afr[13]), "=&v"(afr[14]), "=&v"(afr[15]) \
        : "v"(haddr) : "memory")

// Batch-per-XCD LSTM, R12: flagless. Producers just store h (write-through L1
// -> L2, no drain, no barrier, no flag). Consumers poll-load the h row with
// sc0 (L1-bypass) loads, run the h-MFMAs, and retry iff the accumulator has a
// NaN (sentinel or torn write poisons the whole row -> complete detection).
// Waves are fully decoupled; no per-step __syncthreads.
__global__ __launch_bounds__(256, 1) void k_lstm(const u16* __restrict__ Wt, const u16* __restrict__ Xb,
                                                 u16* __restrict__ hs, const float* __restrict__ bias,
                                                 u32* __restrict__ sync) {
    __shared__ float sG[4 * 136];      // per-wave 8 rows x 16 cols (pitch 17)
    __shared__ int sSlot, sXcc;

    const int tid = threadIdx.x;
    const int lane = tid & 63, wv = tid >> 6;
    const int l16 = lane & 15, quad = lane >> 4;

    // ---- one-time: XCD self-organization (R7/R8-proven; sleep OK here) ----
    if (tid == 0) {
        u32 xcc;
        asm volatile("s_getreg_b32 %0, hwreg(HW_REG_XCC_ID)" : "=s"(xcc));
        xcc &= 7;
        u32 slot = __hip_atomic_fetch_add(sync + xcc * FL, 1u, __ATOMIC_RELAXED, __HIP_MEMORY_SCOPE_AGENT);
        int ok = -1;
        if (slot < 32) {
            int g = 0;
            while (__hip_atomic_load(sync + xcc * FL, __ATOMIC_RELAXED, __HIP_MEMORY_SCOPE_AGENT) < 32u) {
                __builtin_amdgcn_s_sleep(8);
                if (++g > 2000000) { ok = -2; break; }
            }
            if (ok == -1) ok = (int)slot;
        }
        sSlot = ok; sXcc = (int)xcc;
    }
    __syncthreads();
    const int s = sSlot;
    if (s < 0) return;
    const int xcc = sXcc;
    const int b0 = 8 * xcc;

    // gate lane mapping: lanes 0..31 own one h-output each (b=lane>>2, j=lane&3)
    // (lanes 32..63 compute duplicates, store is masked). Halves the serial exp
    // chain vs the old 16-lane x 2-output layout.
    const int gb = (lane >> 2) & 7, gj = lane & 3;
    float bi, bj, bf, bo;
    {
        int hc = s * 16 + wv * 4 + gj;
        bi = bias[hc]; bj = bias[512 + hc]; bf = bias[1024 + hc] + 1.0f; bo = bias[1536 + hc];
    }

    // weight fragments: local col c=l16 -> global col (c>>2)*512 + s*16 + wv*4 + (c&3)
    short8 bfr[20];
    {
        size_t bcol = (size_t)(l16 >> 2) * 512 + s * 16 + wv * 4 + (l16 & 3);
        const u16* wp = Wt + bcol * KDIM + quad * 8;
#pragma unroll
        for (int ks = 0; ks < 20; ++ks) bfr[ks] = *(const short8*)(wp + ks * 32);
    }

    const int bA = l16 & 7;
    float cst = 0.f;
    __syncthreads();

    // x fragments for t=0 (recurrence-independent; 1-step prefetch thereafter)
    short8 xcur[4], xnxt[4];
    {
        const u16* xrow = Xb + ((size_t)b0 + bA) * N_ + quad * 8;
#pragma unroll
        for (int ks = 0; ks < 4; ++ks) xcur[ks] = *(const short8*)(xrow + ks * 32);
    }

    for (int t = 0; t < T_; ++t) {
        // x contribution: independent of h_t, computed before the poll
        floatx4 px = {0.f, 0.f, 0.f, 0.f}, qx = {0.f, 0.f, 0.f, 0.f};
        px = __builtin_amdgcn_mfma_f32_16x16x32_bf16(xcur[0], bfr[16], px, 0, 0, 0);
        qx = __builtin_amdgcn_mfma_f32_16x16x32_bf16(xcur[1], bfr[17], qx, 0, 0, 0);
        px = __builtin_amdgcn_mfma_f32_16x16x32_bf16(xcur[2], bfr[18], px, 0, 0, 0);
        qx = __builtin_amdgcn_mfma_f32_16x16x32_bf16(xcur[3], bfr[19], qx, 0, 0, 0);

        // prefetch next x fragments (completes under the poll latency)
        if (t + 1 < T_) {
            const u16* xrow = Xb + ((size_t)(t + 1) * 64 + b0 + bA) * N_ + quad * 8;
#pragma unroll
            for (int ks = 0; ks < 4; ++ks) xnxt[ks] = *(const short8*)(xrow + ks * 32);
        }

        // poll-load h_t + MFMA + NaN-validate (detection merges with compute)
        short8 afr[16];
        floatx4 p, q;
        u64 haddr = (u64)(uintptr_t)(hs + ((size_t)t * 64 + b0 + bA) * H_ + quad * 8);
        int g = 0;
        for (;;) {
            if (g & 1) { PLOADS("sc0 sc1"); } else { PLOADS("sc0"); }
            p = px; q = qx;
#pragma unroll
            for (int ks = 0; ks < 16; ks += 2) {
                p = __builtin_amdgcn_mfma_f32_16x16x32_bf16(afr[ks],     bfr[ks],     p, 0, 0, 0);
                q = __builtin_amdgcn_mfma_f32_16x16x32_bf16(afr[ks + 1], bfr[ks + 1], q, 0, 0, 0);
            }
            // any NaN bf16 anywhere poisons a full accumulator row -> 1 cmp/lane
            float v = ((p[0] + p[1]) + (p[2] + p[3])) + ((q[0] + q[1]) + (q[2] + q[3]));
            if (__all(v == v)) break;
            if (++g > 20000) break;   // fail-safe: fails LOUDLY (NaN output)
        }
        floatx4 acc = p + q;

        // C/D: row = quad*4+r (rows 0..7 real), col = l16 -> wave-private sG
        if (quad < 2) {
            float* gp = sG + wv * 136 + (quad * 4) * 17 + l16;
#pragma unroll
            for (int r = 0; r < 4; ++r) gp[r * 17] = acc[r];
        }
        asm volatile("s_waitcnt lgkmcnt(0)" ::: "memory");

        // gate math: 32 lanes x 1 output (same-wave LDS relay, no barrier)
        float h;
        {
            const float* gr = sG + wv * 136 + gb * 17;
            float gi = gr[gj]      + bi;
            float gJ = gr[4 + gj]  + bj;
            float gF = gr[8 + gj]  + bf;
            float gO = gr[12 + gj] + bo;
            cst = sigf(gF) * cst + sigf(gi) * tanh_(gJ);
            h = sigf(gO) * tanh_(cst);
        }
        if (lane < 32)
            hs[((size_t)(t + 1) * 64 + b0 + gb) * H_ + s * 16 + wv * 4 + gj] = f2bf(h);

#pragma unroll
        for (int ks = 0; ks < 4; ++ks) xcur[ks] = xnxt[ks];
    }
}

// decoder + loss: rows R = t*64+b of hs[1..512]; 32 rows/block staged in LDS
__global__ __launch_bounds__(256) void k_dec(const u16* __restrict__ hs, const float* __restrict__ Wd,
                                             const float* __restrict__ bd, const float* __restrict__ Y,
                                             float* __restrict__ out) {
    __shared__ u16 sH[32 * H_];
    __shared__ float red[4];
    int tid = threadIdx.x;
    int R0 = blockIdx.x * 32;
    for (int u = tid; u < 2048; u += 256) {
        int row = u >> 6, ch = u & 63;
        *(short8*)(sH + row * H_ + ch * 8) =
            *(const short8*)(hs + (size_t)(64 + R0 + row) * H_ + ch * 8);
    }
    __syncthreads();

    int n = tid & 127, half = tid >> 7;
    float bdv = bd[n];
    float acc[16];
#pragma unroll
    for (int i = 0; i < 16; ++i) acc[i] = 0.f;

    for (int ko = 0; ko < H_ / 8; ++ko) {
        float wv[8];
#pragma unroll
        for (int j = 0; j < 8; ++j) wv[j] = Wd[(ko * 8 + j) * N_ + n];
#pragma unroll
        for (int i = 0; i < 16; ++i) {
            int r = half * 16 + i;
            const uint4 hv = *(const uint4*)(sH + r * H_ + ko * 8);
            acc[i] += __uint_as_float(hv.x << 16) * wv[0] + __uint_as_float(hv.x & 0xFFFF0000u) * wv[1]
                    + __uint_as_float(hv.y << 16) * wv[2] + __uint_as_float(hv.y & 0xFFFF0000u) * wv[3]
                    + __uint_as_float(hv.z << 16) * wv[4] + __uint_as_float(hv.z & 0xFFFF0000u) * wv[5]
                    + __uint_as_float(hv.w << 16) * wv[6] + __uint_as_float(hv.w & 0xFFFF0000u) * wv[7];
        }
    }
    float sse = 0.f;
#pragma unroll
    for (int i = 0; i < 16; ++i) {
        int R = R0 + half * 16 + i;
        int t = R >> 6, b = R & 63;
        float logit = sigf(acc[i] + bdv);
        float d = Y[(size_t)(b * T_ + t) * N_ + n] - logit;
        sse += d * d;
    }
    for (int off = 32; off > 0; off >>= 1) sse += __shfl_down(sse, off, 64);
    if ((tid & 63) == 0) red[tid >> 6] = sse;
    __syncthreads();
    if (tid == 0) {
        float tot = red[0] + red[1] + red[2] + red[3];
        atomicAdd(out, tot * (100.0f / 4194304.0f));
    }
}

extern "C" void kernel_launch(void* const* d_in, const int* in_sizes, int n_in,
                              void* d_out, int out_size, void* d_ws, size_t ws_size,
                              hipStream_t stream) {
    (void)in_sizes; (void)n_in; (void)out_size;
    const float* X  = (const float*)d_in[0];
    const float* Y  = (const float*)d_in[1];
    const float* Wx = (const float*)d_in[2];
    const float* Wh = (const float*)d_in[3];
    const float* bb = (const float*)d_in[4];
    const float* Wd = (const float*)d_in[5];
    const float* bd = (const float*)d_in[6];

    char* ws = (char*)d_ws;
    u32* syncz = (u32*)ws;
    const size_t sync_bytes = 131072;
    u16* hs  = (u16*)(ws + sync_bytes);
    const size_t hs_bytes = (size_t)(T_ + 1) * 64 * H_ * 2;   // 33,619,968
    u16* Xb  = (u16*)(ws + sync_bytes + hs_bytes);
    const size_t xb_bytes = (size_t)T_ * 64 * N_ * 2;         // 8,388,608
    u16* Wt  = (u16*)(ws + sync_bytes + hs_bytes + xb_bytes);
    const size_t need = sync_bytes + hs_bytes + xb_bytes + (size_t)2048 * KDIM * 2;
    if (ws_size < need) return;   // ~44.8 MB scratch required

    (void)hipMemsetAsync(syncz, 0, 65536, stream);            // org counters
    (void)hipMemsetAsync(hs, 0, 64 * H_ * 2, stream);         // h_{-1} = 0 (t=0 rows, NOT NaN)
    (void)hipMemsetAsync(d_out, 0, sizeof(float), stream);

    // NaN-sentinel prefill of hs rows [64, 513*64): 2,097,152 uint4 = 33.5 MB
    k_fill<<<dim3(8192), dim3(256), 0, stream>>>((uint4*)(hs + (size_t)64 * H_));

    k_xb<<<dim3((B_ * T_ * N_) / 256), dim3(256), 0, stream>>>(X, Xb);
    k_wcat<<<dim3((2048 * KDIM) / 256), dim3(256), 0, stream>>>(Wx, Wh, Wt);

    void* args[] = { (void*)&Wt, (void*)&Xb, (void*)&hs, (void*)&bb, (void*)&syncz };
    (void)hipLaunchCooperativeKernel((const void*)k_lstm, dim3(256), dim3(256), args, 0, stream);

    k_dec<<<dim3((B_ * T_) / 32), dim3(256), 0, stream>>>(hs, Wd, bd, Y, (float*)d_out);
}

// Round 3
// 1965.437 us; speedup vs baseline: 1.1896x; 1.1140x over previous
//
#include <hip/hip_runtime.h>
#include <stdint.h>

typedef unsigned short u16;
typedef unsigned int u32;
typedef unsigned long long u64;

#define B_ 64
#define T_ 512
#define N_ 128
#define H_ 512
#define KDIM 640        // H + N
#define FL 32           // u32 per 128B line
// sync lines: [0..7] org counters (agent) only. Consumers poll hs data
// directly against the bf16-NaN sentinel 0x7FC0 (|h|<1 can never produce it).

typedef __attribute__((ext_vector_type(8))) short short8;
typedef __attribute__((ext_vector_type(4))) float floatx4;

__device__ __forceinline__ float sigf(float x) { return 1.0f / (1.0f + __expf(-x)); }
__device__ __forceinline__ float tanh_(float x) { return 1.0f - 2.0f / (1.0f + __expf(2.0f * x)); }

__device__ __forceinline__ u16 f2bf(float x) {
    u32 u = __float_as_uint(x);
    u32 r = (u + 0x7FFFu + ((u >> 16) & 1u)) >> 16;   // RNE
    return (u16)r;
}

// X [B,T,N] fp32 -> Xb [T,B,N] bf16
__global__ __launch_bounds__(256) void k_xb(const float* __restrict__ X, u16* __restrict__ Xb) {
    int i = blockIdx.x * 256 + threadIdx.x;
    int n = i & 127, b = (i >> 7) & 63, t = i >> 13;
    Xb[i] = f2bf(X[(b * T_ + t) * N_ + n]);
}

// Wcat^T [2048 cols][640 k] bf16: rows k<512 from Wh, k>=512 from Wx
__global__ __launch_bounds__(256) void k_wcat(const float* __restrict__ Wx, const float* __restrict__ Wh,
                                              u16* __restrict__ Wt) {
    int i = blockIdx.x * 256 + threadIdx.x;
    int c = i & 2047, k = i >> 11;
    float v = (k < H_) ? Wh[k * 2048 + c] : Wx[(k - H_) * 2048 + c];
    Wt[c * KDIM + k] = f2bf(v);
}

// NaN-prefill hs rows [64, 513*64): 0x7FC0 bf16 sentinel.
__global__ __launch_bounds__(256) void k_fill(uint4* __restrict__ p) {
    int i = blockIdx.x * 256 + threadIdx.x;
    uint4 v; v.x = v.y = v.z = v.w = 0x7FC07FC0u;
    p[i] = v;
}

// 16 L1-bypass dwordx4 loads + drain, all in ONE asm block so the waitcnt
// cannot be separated from the loads (rule-18-safe: MFMAs depend on outputs).
#define PLOADS(SC) \
    asm volatile( \
        "global_load_dwordx4 %0, %16, off " SC "\n\t" \
        "global_load_dwordx4 %1, %16, off offset:64 " SC "\n\t" \
        "global_load_dwordx4 %2, %16, off offset:128 " SC "\n\t" \
        "global_load_dwordx4 %3, %16, off offset:192 " SC "\n\t" \
        "global_load_dwordx4 %4, %16, off offset:256 " SC "\n\t" \
        "global_load_dwordx4 %5, %16, off offset:320 " SC "\n\t" \
        "global_load_dwordx4 %6, %16, off offset:384 " SC "\n\t" \
        "global_load_dwordx4 %7, %16, off offset:448 " SC "\n\t" \
        "global_load_dwordx4 %8, %16, off offset:512 " SC "\n\t" \
        "global_load_dwordx4 %9, %16, off offset:576 " SC "\n\t" \
        "global_load_dwordx4 %10, %16, off offset:640 " SC "\n\t" \
        "global_load_dwordx4 %11, %16, off offset:704 " SC "\n\t" \
        "global_load_dwordx4 %12, %16, off offset:768 " SC "\n\t" \
        "global_load_dwordx4 %13, %16, off offset:832 " SC "\n\t" \
        "global_load_dwordx4 %14, %16, off offset:896 " SC "\n\t" \
        "global_load_dwordx4 %15, %16, off offset:960 " SC "\n\t" \
        "s_waitcnt vmcnt(0)" \
        : "=&v"(afr[0]), "=&v"(afr[1]), "=&v"(afr[2]), "=&v"(afr[3]), \
          "=&v"(afr[4]), "=&v"(afr[5]), "=&v"(afr[6]), "=&v"(afr[7]), \
          "=&v"(afr[8]), "=&v"(afr[9]), "=&v"(afr[10]), "=&v"(afr[11]), \
          "=&v"(afr[12]), "=&v"(afr[13]), "=&v"(afr[14]), "=&v"(afr[15]) \
        : "v"(haddr) : "memory")

#define HMFMA() \
    do { \
        p = px; q = qx; \
        _Pragma("unroll") \
        for (int ks = 0; ks < 16; ks += 2) { \
            p = __builtin_amdgcn_mfma_f32_16x16x32_bf16(afr[ks],     bfr[ks],     p, 0, 0, 0); \
            q = __builtin_amdgcn_mfma_f32_16x16x32_bf16(afr[ks + 1], bfr[ks + 1], q, 0, 0, 0); \
        } \
    } while (0)

// Batch-per-XCD LSTM, R13: single-poller. The 4 waves of a block need
// IDENTICAL h fragments (afr addresses don't depend on wv) -> R12's 4-wave
// polling was 4x redundant L2 traffic (2 MB/XCD/round; ~465 ns/round at
// per-XCD L2 BW -> the measured ~3.9 us/step at ~6 rounds). Now only wave 0
// polls; waves 1-3 wait on an LDS epoch then load once (data guaranteed in
// L2; NaN-validate retry kept as a correctness safety net).
__global__ __launch_bounds__(256, 1) void k_lstm(const u16* __restrict__ Wt, const u16* __restrict__ Xb,
                                                 u16* __restrict__ hs, const float* __restrict__ bias,
                                                 u32* __restrict__ sync) {
    __shared__ float sG[4 * 136];      // per-wave 8 rows x 16 cols (pitch 17)
    __shared__ int sSlot, sXcc, sEpoch;

    const int tid = threadIdx.x;
    const int lane = tid & 63, wv = tid >> 6;
    const int l16 = lane & 15, quad = lane >> 4;

    // ---- one-time: XCD self-organization (R7/R8-proven; sleep OK here) ----
    if (tid == 0) {
        u32 xcc;
        asm volatile("s_getreg_b32 %0, hwreg(HW_REG_XCC_ID)" : "=s"(xcc));
        xcc &= 7;
        u32 slot = __hip_atomic_fetch_add(sync + xcc * FL, 1u, __ATOMIC_RELAXED, __HIP_MEMORY_SCOPE_AGENT);
        int ok = -1;
        if (slot < 32) {
            int g = 0;
            while (__hip_atomic_load(sync + xcc * FL, __ATOMIC_RELAXED, __HIP_MEMORY_SCOPE_AGENT) < 32u) {
                __builtin_amdgcn_s_sleep(8);
                if (++g > 2000000) { ok = -2; break; }
            }
            if (ok == -1) ok = (int)slot;
        }
        sSlot = ok; sXcc = (int)xcc; sEpoch = -1;
    }
    __syncthreads();
    const int s = sSlot;
    if (s < 0) return;
    const int xcc = sXcc;
    const int b0 = 8 * xcc;

    // gate lane mapping: lanes 0..31 own one h-output each (b=lane>>2 &7, j=lane&3)
    const int gb = (lane >> 2) & 7, gj = lane & 3;
    float bi, bj, bf, bo;
    {
        int hc = s * 16 + wv * 4 + gj;
        bi = bias[hc]; bj = bias[512 + hc]; bf = bias[1024 + hc] + 1.0f; bo = bias[1536 + hc];
    }

    // weight fragments: local col c=l16 -> global col (c>>2)*512 + s*16 + wv*4 + (c&3)
    short8 bfr[20];
    {
        size_t bcol = (size_t)(l16 >> 2) * 512 + s * 16 + wv * 4 + (l16 & 3);
        const u16* wp = Wt + bcol * KDIM + quad * 8;
#pragma unroll
        for (int ks = 0; ks < 20; ++ks) bfr[ks] = *(const short8*)(wp + ks * 32);
    }

    const int bA = l16 & 7;
    float cst = 0.f;
    __syncthreads();

    // x fragments for t=0 (recurrence-independent; 1-step prefetch thereafter)
    short8 xcur[4], xnxt[4];
    {
        const u16* xrow = Xb + ((size_t)b0 + bA) * N_ + quad * 8;
#pragma unroll
        for (int ks = 0; ks < 4; ++ks) xcur[ks] = *(const short8*)(xrow + ks * 32);
    }

    for (int t = 0; t < T_; ++t) {
        // x contribution: independent of h_t, computed before the poll
        floatx4 px = {0.f, 0.f, 0.f, 0.f}, qx = {0.f, 0.f, 0.f, 0.f};
        px = __builtin_amdgcn_mfma_f32_16x16x32_bf16(xcur[0], bfr[16], px, 0, 0, 0);
        qx = __builtin_amdgcn_mfma_f32_16x16x32_bf16(xcur[1], bfr[17], qx, 0, 0, 0);
        px = __builtin_amdgcn_mfma_f32_16x16x32_bf16(xcur[2], bfr[18], px, 0, 0, 0);
        qx = __builtin_amdgcn_mfma_f32_16x16x32_bf16(xcur[3], bfr[19], qx, 0, 0, 0);

        // prefetch next x fragments (completes under the poll latency)
        if (t + 1 < T_) {
            const u16* xrow = Xb + ((size_t)(t + 1) * 64 + b0 + bA) * N_ + quad * 8;
#pragma unroll
            for (int ks = 0; ks < 4; ++ks) xnxt[ks] = *(const short8*)(xrow + ks * 32);
        }

        short8 afr[16];
        floatx4 p, q;
        u64 haddr = (u64)(uintptr_t)(hs + ((size_t)t * 64 + b0 + bA) * H_ + quad * 8);

        if (wv == 0) {
            // single poller: load + MFMA + NaN-validate (detection merges
            // with compute; a torn/sentinel u16 poisons the accumulator row)
            int g = 0;
            for (;;) {
                if (g & 1) { PLOADS("sc0 sc1"); } else { PLOADS("sc0"); }
                HMFMA();
                float v = ((p[0] + p[1]) + (p[2] + p[3])) + ((q[0] + q[1]) + (q[2] + q[3]));
                if (__all(v == v)) break;
                if (++g > 100000) break;   // fail-safe: fails LOUDLY (NaN out)
            }
            if (lane == 0)
                __hip_atomic_store(&sEpoch, t, __ATOMIC_RELAXED, __HIP_MEMORY_SCOPE_WORKGROUP);
        } else {
            // waves 1-3: cheap LDS spin until wave 0 certifies h_t is in L2,
            // then ONE fragment load (sc0: fresh addresses, but bypass any
            // stale L1 lines wave 0's polling may have left behind).
            int g = 0;
            while (__hip_atomic_load(&sEpoch, __ATOMIC_RELAXED, __HIP_MEMORY_SCOPE_WORKGROUP) < t) {
                if (++g > 30000000) break;   // fail-safe
            }
            g = 0;
            for (;;) {
                if (g & 1) { PLOADS("sc0 sc1"); } else { PLOADS("sc0"); }
                HMFMA();
                float v = ((p[0] + p[1]) + (p[2] + p[3])) + ((q[0] + q[1]) + (q[2] + q[3]));
                if (__all(v == v)) break;    // expected: 1 round
                if (++g > 100000) break;     // fail-safe
            }
        }
        floatx4 acc = p + q;

        // C/D: row = quad*4+r (rows 0..7 real), col = l16 -> wave-private sG
        if (quad < 2) {
            float* gp = sG + wv * 136 + (quad * 4) * 17 + l16;
#pragma unroll
            for (int r = 0; r < 4; ++r) gp[r * 17] = acc[r];
        }
        asm volatile("s_waitcnt lgkmcnt(0)" ::: "memory");

        // gate math: 32 lanes x 1 output (same-wave LDS relay, no barrier)
        float h;
        {
            const float* gr = sG + wv * 136 + gb * 17;
            float gi = gr[gj]      + bi;
            float gJ = gr[4 + gj]  + bj;
            float gF = gr[8 + gj]  + bf;
            float gO = gr[12 + gj] + bo;
            cst = sigf(gF) * cst + sigf(gi) * tanh_(gJ);
            h = sigf(gO) * tanh_(cst);
        }
        if (lane < 32)
            hs[((size_t)(t + 1) * 64 + b0 + gb) * H_ + s * 16 + wv * 4 + gj] = f2bf(h);

#pragma unroll
        for (int ks = 0; ks < 4; ++ks) xcur[ks] = xnxt[ks];
    }
}

// decoder + loss: rows R = t*64+b of hs[1..512]; 32 rows/block staged in LDS
__global__ __launch_bounds__(256) void k_dec(const u16* __restrict__ hs, const float* __restrict__ Wd,
                                             const float* __restrict__ bd, const float* __restrict__ Y,
                                             float* __restrict__ out) {
    __shared__ u16 sH[32 * H_];
    __shared__ float red[4];
    int tid = threadIdx.x;
    int R0 = blockIdx.x * 32;
    for (int u = tid; u < 2048; u += 256) {
        int row = u >> 6, ch = u & 63;
        *(short8*)(sH + row * H_ + ch * 8) =
            *(const short8*)(hs + (size_t)(64 + R0 + row) * H_ + ch * 8);
    }
    __syncthreads();

    int n = tid & 127, half = tid >> 7;
    float bdv = bd[n];
    float acc[16];
#pragma unroll
    for (int i = 0; i < 16; ++i) acc[i] = 0.f;

    for (int ko = 0; ko < H_ / 8; ++ko) {
        float wv[8];
#pragma unroll
        for (int j = 0; j < 8; ++j) wv[j] = Wd[(ko * 8 + j) * N_ + n];
#pragma unroll
        for (int i = 0; i < 16; ++i) {
            int r = half * 16 + i;
            const uint4 hv = *(const uint4*)(sH + r * H_ + ko * 8);
            acc[i] += __uint_as_float(hv.x << 16) * wv[0] + __uint_as_float(hv.x & 0xFFFF0000u) * wv[1]
                    + __uint_as_float(hv.y << 16) * wv[2] + __uint_as_float(hv.y & 0xFFFF0000u) * wv[3]
                    + __uint_as_float(hv.z << 16) * wv[4] + __uint_as_float(hv.z & 0xFFFF0000u) * wv[5]
                    + __uint_as_float(hv.w << 16) * wv[6] + __uint_as_float(hv.w & 0xFFFF0000u) * wv[7];
        }
    }
    float sse = 0.f;
#pragma unroll
    for (int i = 0; i < 16; ++i) {
        int R = R0 + half * 16 + i;
        int t = R >> 6, b = R & 63;
        float logit = sigf(acc[i] + bdv);
        float d = Y[(size_t)(b * T_ + t) * N_ + n] - logit;
        sse += d * d;
    }
    for (int off = 32; off > 0; off >>= 1) sse += __shfl_down(sse, off, 64);
    if ((tid & 63) == 0) red[tid >> 6] = sse;
    __syncthreads();
    if (tid == 0) {
        float tot = red[0] + red[1] + red[2] + red[3];
        atomicAdd(out, tot * (100.0f / 4194304.0f));
    }
}

extern "C" void kernel_launch(void* const* d_in, const int* in_sizes, int n_in,
                              void* d_out, int out_size, void* d_ws, size_t ws_size,
                              hipStream_t stream) {
    (void)in_sizes; (void)n_in; (void)out_size;
    const float* X  = (const float*)d_in[0];
    const float* Y  = (const float*)d_in[1];
    const float* Wx = (const float*)d_in[2];
    const float* Wh = (const float*)d_in[3];
    const float* bb = (const float*)d_in[4];
    const float* Wd = (const float*)d_in[5];
    const float* bd = (const float*)d_in[6];

    char* ws = (char*)d_ws;
    u32* syncz = (u32*)ws;
    const size_t sync_bytes = 131072;
    u16* hs  = (u16*)(ws + sync_bytes);
    const size_t hs_bytes = (size_t)(T_ + 1) * 64 * H_ * 2;   // 33,619,968
    u16* Xb  = (u16*)(ws + sync_bytes + hs_bytes);
    const size_t xb_bytes = (size_t)T_ * 64 * N_ * 2;         // 8,388,608
    u16* Wt  = (u16*)(ws + sync_bytes + hs_bytes + xb_bytes);
    const size_t need = sync_bytes + hs_bytes + xb_bytes + (size_t)2048 * KDIM * 2;
    if (ws_size < need) return;   // ~44.8 MB scratch required

    (void)hipMemsetAsync(syncz, 0, 65536, stream);            // org counters
    (void)hipMemsetAsync(hs, 0, 64 * H_ * 2, stream);         // h_{-1} = 0 (t=0 rows, NOT NaN)
    (void)hipMemsetAsync(d_out, 0, sizeof(float), stream);

    // NaN-sentinel prefill of hs rows [64, 513*64): 2,097,152 uint4 = 33.5 MB
    k_fill<<<dim3(8192), dim3(256), 0, stream>>>((uint4*)(hs + (size_t)64 * H_));

    k_xb<<<dim3((B_ * T_ * N_) / 256), dim3(256), 0, stream>>>(X, Xb);
    k_wcat<<<dim3((2048 * KDIM) / 256), dim3(256), 0, stream>>>(Wx, Wh, Wt);

    void* args[] = { (void*)&Wt, (void*)&Xb, (void*)&hs, (void*)&bb, (void*)&syncz };
    (void)hipLaunchCooperativeKernel((const void*)k_lstm, dim3(256), dim3(256), args, 0, stream);

    k_dec<<<dim3((B_ * T_) / 32), dim3(256), 0, stream>>>(hs, Wd, bd, Y, (float*)d_out);
}

// Round 4
// 1737.023 us; speedup vs baseline: 1.3460x; 1.1315x over previous
//
#include <hip/hip_runtime.h>
#include <stdint.h>

typedef unsigned short u16;
typedef unsigned int u32;
typedef unsigned long long u64;

#define B_ 64
#define T_ 512
#define N_ 128
#define H_ 512
#define KDIM 640        // H + N
#define FL 32           // u32 per 128B line
// sync lines: [0..7] org counters (agent) only. Consumers poll hs data
// directly against the bf16-NaN sentinel 0x7FC0 (|h|<1 can never produce it).

typedef __attribute__((ext_vector_type(8))) short short8;
typedef __attribute__((ext_vector_type(4))) float floatx4;
typedef __attribute__((ext_vector_type(4))) u32 u32x4;

__device__ __forceinline__ float sigf(float x) { return 1.0f / (1.0f + __expf(-x)); }
__device__ __forceinline__ float tanh_(float x) { return 1.0f - 2.0f / (1.0f + __expf(2.0f * x)); }

__device__ __forceinline__ u16 f2bf(float x) {
    u32 u = __float_as_uint(x);
    u32 r = (u + 0x7FFFu + ((u >> 16) & 1u)) >> 16;   // RNE
    return (u16)r;
}

// true iff NEITHER bf16 half of x equals the 0x7FC0 sentinel.
// t = x ^ 0x7FC07FC0; halfword-zero detect: (t-0x00010001) & ~t & 0x80008000.
// (borrow false-positive only when low half IS the sentinel -> already caught)
__device__ __forceinline__ bool clean2(u32 x) {
    u32 t = x ^ 0x7FC07FC0u;
    return (((t - 0x00010001u) & ~t) & 0x80008000u) == 0u;
}

// X [B,T,N] fp32 -> Xb [T,B,N] bf16
__global__ __launch_bounds__(256) void k_xb(const float* __restrict__ X, u16* __restrict__ Xb) {
    int i = blockIdx.x * 256 + threadIdx.x;
    int n = i & 127, b = (i >> 7) & 63, t = i >> 13;
    Xb[i] = f2bf(X[(b * T_ + t) * N_ + n]);
}

// Wcat^T [2048 cols][640 k] bf16: rows k<512 from Wh, k>=512 from Wx
__global__ __launch_bounds__(256) void k_wcat(const float* __restrict__ Wx, const float* __restrict__ Wh,
                                              u16* __restrict__ Wt) {
    int i = blockIdx.x * 256 + threadIdx.x;
    int c = i & 2047, k = i >> 11;
    float v = (k < H_) ? Wh[k * 2048 + c] : Wx[(k - H_) * 2048 + c];
    Wt[c * KDIM + k] = f2bf(v);
}

// NaN-prefill hs rows [64, 513*64): 0x7FC0 bf16 sentinel.
__global__ __launch_bounds__(256) void k_fill(uint4* __restrict__ p) {
    int i = blockIdx.x * 256 + threadIdx.x;
    uint4 v; v.x = v.y = v.z = v.w = 0x7FC07FC0u;
    p[i] = v;
}

// 16 L1-bypass dwordx4 loads + drain, all in ONE asm block so the waitcnt
// cannot be separated from the loads (rule-18-safe: MFMAs depend on outputs).
#define PLOADS(SC) \
    asm volatile( \
        "global_load_dwordx4 %0, %16, off " SC "\n\t" \
        "global_load_dwordx4 %1, %16, off offset:64 " SC "\n\t" \
        "global_load_dwordx4 %2, %16, off offset:128 " SC "\n\t" \
        "global_load_dwordx4 %3, %16, off offset:192 " SC "\n\t" \
        "global_load_dwordx4 %4, %16, off offset:256 " SC "\n\t" \
        "global_load_dwordx4 %5, %16, off offset:320 " SC "\n\t" \
        "global_load_dwordx4 %6, %16, off offset:384 " SC "\n\t" \
        "global_load_dwordx4 %7, %16, off offset:448 " SC "\n\t" \
        "global_load_dwordx4 %8, %16, off offset:512 " SC "\n\t" \
        "global_load_dwordx4 %9, %16, off offset:576 " SC "\n\t" \
        "global_load_dwordx4 %10, %16, off offset:640 " SC "\n\t" \
        "global_load_dwordx4 %11, %16, off offset:704 " SC "\n\t" \
        "global_load_dwordx4 %12, %16, off offset:768 " SC "\n\t" \
        "global_load_dwordx4 %13, %16, off offset:832 " SC "\n\t" \
        "global_load_dwordx4 %14, %16, off offset:896 " SC "\n\t" \
        "global_load_dwordx4 %15, %16, off offset:960 " SC "\n\t" \
        "s_waitcnt vmcnt(0)" \
        : "=&v"(afr[0]), "=&v"(afr[1]), "=&v"(afr[2]), "=&v"(afr[3]), \
          "=&v"(afr[4]), "=&v"(afr[5]), "=&v"(afr[6]), "=&v"(afr[7]), \
          "=&v"(afr[8]), "=&v"(afr[9]), "=&v"(afr[10]), "=&v"(afr[11]), \
          "=&v"(afr[12]), "=&v"(afr[13]), "=&v"(afr[14]), "=&v"(afr[15]) \
        : "v"(haddr) : "memory")

#define CANARY(SC) \
    asm volatile("global_load_dwordx4 %0, %1, off " SC "\n\ts_waitcnt vmcnt(0)" \
                 : "=&v"(cv) : "v"(caddr) : "memory")

#define HMFMA() \
    do { \
        p = px; q = qx; \
        _Pragma("unroll") \
        for (int ks = 0; ks < 16; ks += 2) { \
            p = __builtin_amdgcn_mfma_f32_16x16x32_bf16(afr[ks],     bfr[ks],     p, 0, 0, 0); \
            q = __builtin_amdgcn_mfma_f32_16x16x32_bf16(afr[ks + 1], bfr[ks + 1], q, 0, 0, 0); \
        } \
    } while (0)

// Batch-per-XCD LSTM, R14: canary polling, zero cross-wave sync.
// Row 0 of the XCD's 8-row h(t) tile holds 4 cols from EVERY producer-wave
// (128 x 8B segments), and each producer-wave's 8 row-stores issue in one
// instruction. So "row 0 NaN-free" => all producers issued their stores.
// Each wave independently polls the 1KB canary (1 dwordx4/lane + bit-check,
// ~8x cheaper per round than the old full 16KB+MFMA round), then runs its
// full load+MFMA ONCE (NaN-validate retry kept as straggler safety net).
// Deleted: LDS epoch relay, per-step __syncthreads, waves-1-3 second pass.
// Implicit pacing: no wave passes canary(t+1) before all waves stored step t.
__global__ __launch_bounds__(256, 1) void k_lstm(const u16* __restrict__ Wt, const u16* __restrict__ Xb,
                                                 u16* __restrict__ hs, const float* __restrict__ bias,
                                                 u32* __restrict__ sync) {
    __shared__ float sG[4 * 136];      // per-wave 8 rows x 16 cols (pitch 17)
    __shared__ int sSlot, sXcc;

    const int tid = threadIdx.x;
    const int lane = tid & 63, wv = tid >> 6;
    const int l16 = lane & 15, quad = lane >> 4;

    // ---- one-time: XCD self-organization (R7/R8-proven; sleep OK here) ----
    if (tid == 0) {
        u32 xcc;
        asm volatile("s_getreg_b32 %0, hwreg(HW_REG_XCC_ID)" : "=s"(xcc));
        xcc &= 7;
        u32 slot = __hip_atomic_fetch_add(sync + xcc * FL, 1u, __ATOMIC_RELAXED, __HIP_MEMORY_SCOPE_AGENT);
        int ok = -1;
        if (slot < 32) {
            int g = 0;
            while (__hip_atomic_load(sync + xcc * FL, __ATOMIC_RELAXED, __HIP_MEMORY_SCOPE_AGENT) < 32u) {
                __builtin_amdgcn_s_sleep(8);
                if (++g > 2000000) { ok = -2; break; }
            }
            if (ok == -1) ok = (int)slot;
        }
        sSlot = ok; sXcc = (int)xcc;
    }
    __syncthreads();
    const int s = sSlot;
    if (s < 0) return;
    const int xcc = sXcc;
    const int b0 = 8 * xcc;

    // gate lane mapping: lanes 0..31 own one h-output each (b=(lane>>2)&7, j=lane&3)
    const int gb = (lane >> 2) & 7, gj = lane & 3;
    float bi, bj, bf, bo;
    {
        int hc = s * 16 + wv * 4 + gj;
        bi = bias[hc]; bj = bias[512 + hc]; bf = bias[1024 + hc] + 1.0f; bo = bias[1536 + hc];
    }

    // weight fragments: local col c=l16 -> global col (c>>2)*512 + s*16 + wv*4 + (c&3)
    short8 bfr[20];
    {
        size_t bcol = (size_t)(l16 >> 2) * 512 + s * 16 + wv * 4 + (l16 & 3);
        const u16* wp = Wt + bcol * KDIM + quad * 8;
#pragma unroll
        for (int ks = 0; ks < 20; ++ks) bfr[ks] = *(const short8*)(wp + ks * 32);
    }

    const int bA = l16 & 7;
    float cst = 0.f;
    __syncthreads();

    // x fragments for t=0 (recurrence-independent; 1-step prefetch thereafter)
    short8 xcur[4], xnxt[4];
    {
        const u16* xrow = Xb + ((size_t)b0 + bA) * N_ + quad * 8;
#pragma unroll
        for (int ks = 0; ks < 4; ++ks) xcur[ks] = *(const short8*)(xrow + ks * 32);
    }

    for (int t = 0; t < T_; ++t) {
        // x contribution: independent of h_t, computed before the poll
        floatx4 px = {0.f, 0.f, 0.f, 0.f}, qx = {0.f, 0.f, 0.f, 0.f};
        px = __builtin_amdgcn_mfma_f32_16x16x32_bf16(xcur[0], bfr[16], px, 0, 0, 0);
        qx = __builtin_amdgcn_mfma_f32_16x16x32_bf16(xcur[1], bfr[17], qx, 0, 0, 0);
        px = __builtin_amdgcn_mfma_f32_16x16x32_bf16(xcur[2], bfr[18], px, 0, 0, 0);
        qx = __builtin_amdgcn_mfma_f32_16x16x32_bf16(xcur[3], bfr[19], qx, 0, 0, 0);

        // prefetch next x fragments (completes under the poll latency)
        if (t + 1 < T_) {
            const u16* xrow = Xb + ((size_t)(t + 1) * 64 + b0 + bA) * N_ + quad * 8;
#pragma unroll
            for (int ks = 0; ks < 4; ++ks) xnxt[ks] = *(const short8*)(xrow + ks * 32);
        }

        // ---- canary poll: row 0 (batch b0) of h(t), 64 lanes x 16B = 1KB ----
        {
            u64 caddr = (u64)(uintptr_t)(hs + ((size_t)t * 64 + b0) * H_ + lane * 8);
            u32x4 cv;
            int g = 0;
            for (;;) {
                if (g & 1) { CANARY("sc0 sc1"); } else { CANARY("sc0"); }
                bool clean = clean2(cv[0]) && clean2(cv[1]) && clean2(cv[2]) && clean2(cv[3]);
                if (__all(clean)) break;
                if (++g > 3000000) break;   // fail-safe (full-load validate still guards)
            }
        }

        // ---- full load + MFMA + NaN-validate (expected 1 round) ----
        short8 afr[16];
        floatx4 p, q;
        u64 haddr = (u64)(uintptr_t)(hs + ((size_t)t * 64 + b0 + bA) * H_ + quad * 8);
        {
            int g = 0;
            for (;;) {
                if (g & 1) { PLOADS("sc0 sc1"); } else { PLOADS("sc0"); }
                HMFMA();
                float v = ((p[0] + p[1]) + (p[2] + p[3])) + ((q[0] + q[1]) + (q[2] + q[3]));
                if (__all(v == v)) break;
                if (++g > 100000) break;   // fail-safe: fails LOUDLY (NaN out)
            }
        }
        floatx4 acc = p + q;

        // C/D: row = quad*4+r (rows 0..7 real), col = l16 -> wave-private sG
        if (quad < 2) {
            float* gp = sG + wv * 136 + (quad * 4) * 17 + l16;
#pragma unroll
            for (int r = 0; r < 4; ++r) gp[r * 17] = acc[r];
        }
        asm volatile("s_waitcnt lgkmcnt(0)" ::: "memory");

        // gate math: 32 lanes x 1 output (same-wave LDS relay, no barrier)
        float h;
        {
            const float* gr = sG + wv * 136 + gb * 17;
            float gi = gr[gj]      + bi;
            float gJ = gr[4 + gj]  + bj;
            float gF = gr[8 + gj]  + bf;
            float gO = gr[12 + gj] + bo;
            cst = sigf(gF) * cst + sigf(gi) * tanh_(gJ);
            h = sigf(gO) * tanh_(cst);
        }
        // pair lanes (gj even | odd) -> one u32 store per 2 cols
        float hn = __shfl_xor(h, 1, 64);
        if (lane < 32 && (gj & 1) == 0) {
            u32 pk = ((u32)f2bf(hn) << 16) | (u32)f2bf(h);
            *(u32*)(hs + ((size_t)(t + 1) * 64 + b0 + gb) * H_ + s * 16 + wv * 4 + gj) = pk;
        }

#pragma unroll
        for (int ks = 0; ks < 4; ++ks) xcur[ks] = xnxt[ks];
    }
}

// decoder + loss: rows R = t*64+b of hs[1..512]; 32 rows/block staged in LDS
__global__ __launch_bounds__(256) void k_dec(const u16* __restrict__ hs, const float* __restrict__ Wd,
                                             const float* __restrict__ bd, const float* __restrict__ Y,
                                             float* __restrict__ out) {
    __shared__ u16 sH[32 * H_];
    __shared__ float red[4];
    int tid = threadIdx.x;
    int R0 = blockIdx.x * 32;
    for (int u = tid; u < 2048; u += 256) {
        int row = u >> 6, ch = u & 63;
        *(short8*)(sH + row * H_ + ch * 8) =
            *(const short8*)(hs + (size_t)(64 + R0 + row) * H_ + ch * 8);
    }
    __syncthreads();

    int n = tid & 127, half = tid >> 7;
    float bdv = bd[n];
    float acc[16];
#pragma unroll
    for (int i = 0; i < 16; ++i) acc[i] = 0.f;

    for (int ko = 0; ko < H_ / 8; ++ko) {
        float wv[8];
#pragma unroll
        for (int j = 0; j < 8; ++j) wv[j] = Wd[(ko * 8 + j) * N_ + n];
#pragma unroll
        for (int i = 0; i < 16; ++i) {
            int r = half * 16 + i;
            const uint4 hv = *(const uint4*)(sH + r * H_ + ko * 8);
            acc[i] += __uint_as_float(hv.x << 16) * wv[0] + __uint_as_float(hv.x & 0xFFFF0000u) * wv[1]
                    + __uint_as_float(hv.y << 16) * wv[2] + __uint_as_float(hv.y & 0xFFFF0000u) * wv[3]
                    + __uint_as_float(hv.z << 16) * wv[4] + __uint_as_float(hv.z & 0xFFFF0000u) * wv[5]
                    + __uint_as_float(hv.w << 16) * wv[6] + __uint_as_float(hv.w & 0xFFFF0000u) * wv[7];
        }
    }
    float sse = 0.f;
#pragma unroll
    for (int i = 0; i < 16; ++i) {
        int R = R0 + half * 16 + i;
        int t = R >> 6, b = R & 63;
        float logit = sigf(acc[i] + bdv);
        float d = Y[(size_t)(b * T_ + t) * N_ + n] - logit;
        sse += d * d;
    }
    for (int off = 32; off > 0; off >>= 1) sse += __shfl_down(sse, off, 64);
    if ((tid & 63) == 0) red[tid >> 6] = sse;
    __syncthreads();
    if (tid == 0) {
        float tot = red[0] + red[1] + red[2] + red[3];
        atomicAdd(out, tot * (100.0f / 4194304.0f));
    }
}

extern "C" void kernel_launch(void* const* d_in, const int* in_sizes, int n_in,
                              void* d_out, int out_size, void* d_ws, size_t ws_size,
                              hipStream_t stream) {
    (void)in_sizes; (void)n_in; (void)out_size;
    const float* X  = (const float*)d_in[0];
    const float* Y  = (const float*)d_in[1];
    const float* Wx = (const float*)d_in[2];
    const float* Wh = (const float*)d_in[3];
    const float* bb = (const float*)d_in[4];
    const float* Wd = (const float*)d_in[5];
    const float* bd = (const float*)d_in[6];

    char* ws = (char*)d_ws;
    u32* syncz = (u32*)ws;
    const size_t sync_bytes = 131072;
    u16* hs  = (u16*)(ws + sync_bytes);
    const size_t hs_bytes = (size_t)(T_ + 1) * 64 * H_ * 2;   // 33,619,968
    u16* Xb  = (u16*)(ws + sync_bytes + hs_bytes);
    const size_t xb_bytes = (size_t)T_ * 64 * N_ * 2;         // 8,388,608
    u16* Wt  = (u16*)(ws + sync_bytes + hs_bytes + xb_bytes);
    const size_t need = sync_bytes + hs_bytes + xb_bytes + (size_t)2048 * KDIM * 2;
    if (ws_size < need) return;   // ~44.8 MB scratch required

    (void)hipMemsetAsync(syncz, 0, 65536, stream);            // org counters
    (void)hipMemsetAsync(hs, 0, 64 * H_ * 2, stream);         // h_{-1} = 0 (t=0 rows, NOT NaN)
    (void)hipMemsetAsync(d_out, 0, sizeof(float), stream);

    // NaN-sentinel prefill of hs rows [64, 513*64): 2,097,152 uint4 = 33.5 MB
    k_fill<<<dim3(8192), dim3(256), 0, stream>>>((uint4*)(hs + (size_t)64 * H_));

    k_xb<<<dim3((B_ * T_ * N_) / 256), dim3(256), 0, stream>>>(X, Xb);
    k_wcat<<<dim3((2048 * KDIM) / 256), dim3(256), 0, stream>>>(Wx, Wh, Wt);

    void* args[] = { (void*)&Wt, (void*)&Xb, (void*)&hs, (void*)&bb, (void*)&syncz };
    (void)hipLaunchCooperativeKernel((const void*)k_lstm, dim3(256), dim3(256), args, 0, stream);

    k_dec<<<dim3((B_ * T_) / 32), dim3(256), 0, stream>>>(hs, Wd, bd, Y, (float*)d_out);
}

// Round 5
// 1341.358 us; speedup vs baseline: 1.7431x; 1.2950x over previous
//
#include <hip/hip_runtime.h>
#include <stdint.h>

typedef unsigned short u16;
typedef unsigned int u32;
typedef unsigned long long u64;

#define B_ 64
#define T_ 512
#define N_ 128
#define H_ 512
#define KDIM 640        // H + N
#define FL 32           // u32 per 128B line
// sync lines: [0..7] org counters (agent) only. Consumers poll hs data
// directly against the bf16-NaN sentinel 0x7FC0 (|h|<1 can never produce it).

typedef __attribute__((ext_vector_type(8))) short short8;
typedef __attribute__((ext_vector_type(4))) float floatx4;
typedef __attribute__((ext_vector_type(4))) u32 u32x4;

__device__ __forceinline__ float sigf(float x) { return 1.0f / (1.0f + __expf(-x)); }
__device__ __forceinline__ float tanh_(float x) { return 1.0f - 2.0f / (1.0f + __expf(2.0f * x)); }

__device__ __forceinline__ u16 f2bf(float x) {
    u32 u = __float_as_uint(x);
    u32 r = (u + 0x7FFFu + ((u >> 16) & 1u)) >> 16;   // RNE
    return (u16)r;
}

// X [B,T,N] fp32 -> Xb [T,B,N] bf16
__global__ __launch_bounds__(256) void k_xb(const float* __restrict__ X, u16* __restrict__ Xb) {
    int i = blockIdx.x * 256 + threadIdx.x;
    int n = i & 127, b = (i >> 7) & 63, t = i >> 13;
    Xb[i] = f2bf(X[(b * T_ + t) * N_ + n]);
}

// Wcat^T [2048 cols][640 k] bf16: rows k<512 from Wh, k>=512 from Wx
__global__ __launch_bounds__(256) void k_wcat(const float* __restrict__ Wx, const float* __restrict__ Wh,
                                              u16* __restrict__ Wt) {
    int i = blockIdx.x * 256 + threadIdx.x;
    int c = i & 2047, k = i >> 11;
    float v = (k < H_) ? Wh[k * 2048 + c] : Wx[(k - H_) * 2048 + c];
    Wt[c * KDIM + k] = f2bf(v);
}

// NaN-prefill hs rows [64, 513*64): 0x7FC0 bf16 sentinel.
__global__ __launch_bounds__(256) void k_fill(uint4* __restrict__ p) {
    int i = blockIdx.x * 256 + threadIdx.x;
    uint4 v; v.x = v.y = v.z = v.w = 0x7FC07FC0u;
    p[i] = v;
}

// Full 8KB h-tile load: lane reads 16B from each of the 8 batch rows (row
// stride 1024B; global offset imm is 13-bit signed, so rows 4-7 go through a
// second base). ONE asm block so the vmcnt(0) can't be separated (rule 18).
#define TLOADS(SC) \
    asm volatile( \
        "global_load_dwordx4 %0, %8, off " SC "\n\t" \
        "global_load_dwordx4 %1, %8, off offset:1024 " SC "\n\t" \
        "global_load_dwordx4 %2, %8, off offset:2048 " SC "\n\t" \
        "global_load_dwordx4 %3, %8, off offset:3072 " SC "\n\t" \
        "global_load_dwordx4 %4, %9, off " SC "\n\t" \
        "global_load_dwordx4 %5, %9, off offset:1024 " SC "\n\t" \
        "global_load_dwordx4 %6, %9, off offset:2048 " SC "\n\t" \
        "global_load_dwordx4 %7, %9, off offset:3072 " SC "\n\t" \
        "s_waitcnt vmcnt(0)" \
        : "=&v"(ch[0]), "=&v"(ch[1]), "=&v"(ch[2]), "=&v"(ch[3]), \
          "=&v"(ch[4]), "=&v"(ch[5]), "=&v"(ch[6]), "=&v"(ch[7]) \
        : "v"(ha0), "v"(ha1) : "memory")

// Batch-per-XCD LSTM, R15: certified full-tile polling + wave-private LDS.
// The whole h(t) tile an XCD consumes is just 8KB (8 batches x 512 cols).
// Each wave independently poll-loads the full tile (8 coalesced dwordx4/lane)
// and bit-checks every word against the sentinel: clean => ALL producer
// stores are VISIBLE (u32 store granularity = check granularity, no tearing).
// Detection, validation and fetch merge into one stage -> no MFMA retries
// (R14 spent ~3 garbage 16KB+MFMA rounds/step on rows 1-7 lagging the canary).
// The certified tile is staged to a wave-private XOR-swizzled LDS region and
// MFMA A-fragments are ds_read from it. Zero barriers, zero cross-wave sync.
__global__ __launch_bounds__(256, 1) void k_lstm(const u16* __restrict__ Wt, const u16* __restrict__ Xb,
                                                 u16* __restrict__ hs, const float* __restrict__ bias,
                                                 u32* __restrict__ sync) {
    __shared__ u16 sT[4][4096];        // per-wave 8KB certified h-tile (XOR-swizzled)
    __shared__ float sG[4 * 136];      // per-wave 8 rows x 16 cols (pitch 17)
    __shared__ int sSlot, sXcc;

    const int tid = threadIdx.x;
    const int lane = tid & 63, wv = tid >> 6;
    const int l16 = lane & 15, quad = lane >> 4;

    // ---- one-time: XCD self-organization (R7/R8-proven; sleep OK here) ----
    if (tid == 0) {
        u32 xcc;
        asm volatile("s_getreg_b32 %0, hwreg(HW_REG_XCC_ID)" : "=s"(xcc));
        xcc &= 7;
        u32 slot = __hip_atomic_fetch_add(sync + xcc * FL, 1u, __ATOMIC_RELAXED, __HIP_MEMORY_SCOPE_AGENT);
        int ok = -1;
        if (slot < 32) {
            int g = 0;
            while (__hip_atomic_load(sync + xcc * FL, __ATOMIC_RELAXED, __HIP_MEMORY_SCOPE_AGENT) < 32u) {
                __builtin_amdgcn_s_sleep(8);
                if (++g > 2000000) { ok = -2; break; }
            }
            if (ok == -1) ok = (int)slot;
        }
        sSlot = ok; sXcc = (int)xcc;
    }
    __syncthreads();
    const int s = sSlot;
    if (s < 0) return;
    const int xcc = sXcc;
    const int b0 = 8 * xcc;

    // gate lane mapping: lanes 0..31 own one h-output each (b=(lane>>2)&7, j=lane&3)
    const int gb = (lane >> 2) & 7, gj = lane & 3;
    float bi, bj, bf, bo;
    {
        int hc = s * 16 + wv * 4 + gj;
        bi = bias[hc]; bj = bias[512 + hc]; bf = bias[1024 + hc] + 1.0f; bo = bias[1536 + hc];
    }

    // weight fragments: local col c=l16 -> global col (c>>2)*512 + s*16 + wv*4 + (c&3)
    short8 bfr[20];
    {
        size_t bcol = (size_t)(l16 >> 2) * 512 + s * 16 + wv * 4 + (l16 & 3);
        const u16* wp = Wt + bcol * KDIM + quad * 8;
#pragma unroll
        for (int ks = 0; ks < 20; ++ks) bfr[ks] = *(const short8*)(wp + ks * 32);
    }

    const int bA = l16 & 7;
    float cst = 0.f;
    __syncthreads();

    // x fragments for t=0 (recurrence-independent; 1-step prefetch thereafter)
    short8 xcur[4], xnxt[4];
    {
        const u16* xrow = Xb + ((size_t)b0 + bA) * N_ + quad * 8;
#pragma unroll
        for (int ks = 0; ks < 4; ++ks) xcur[ks] = *(const short8*)(xrow + ks * 32);
    }

    char* wbase = (char*)&sT[wv][0];

    for (int t = 0; t < T_; ++t) {
        // x contribution: independent of h_t, computed before the poll
        floatx4 px = {0.f, 0.f, 0.f, 0.f}, qx = {0.f, 0.f, 0.f, 0.f};
        px = __builtin_amdgcn_mfma_f32_16x16x32_bf16(xcur[0], bfr[16], px, 0, 0, 0);
        qx = __builtin_amdgcn_mfma_f32_16x16x32_bf16(xcur[1], bfr[17], qx, 0, 0, 0);
        px = __builtin_amdgcn_mfma_f32_16x16x32_bf16(xcur[2], bfr[18], px, 0, 0, 0);
        qx = __builtin_amdgcn_mfma_f32_16x16x32_bf16(xcur[3], bfr[19], qx, 0, 0, 0);

        // prefetch next x fragments (completes under the poll latency)
        if (t + 1 < T_) {
            const u16* xrow = Xb + ((size_t)(t + 1) * 64 + b0 + bA) * N_ + quad * 8;
#pragma unroll
            for (int ks = 0; ks < 4; ++ks) xnxt[ks] = *(const short8*)(xrow + ks * 32);
        }

        // ---- certified full-tile poll: 8KB, all 8 rows, sentinel bit-check ----
        u32x4 ch[8];
        {
            u64 ha0 = (u64)(uintptr_t)(hs + ((size_t)t * 64 + b0) * H_ + lane * 8);
            u64 ha1 = ha0 + 4096;
            int g = 0;
            for (;;) {
                if (g & 1) { TLOADS("sc0 sc1"); } else { TLOADS("sc0"); }
                u32 a = 0;
#pragma unroll
                for (int c = 0; c < 8; ++c) {
#pragma unroll
                    for (int k = 0; k < 4; ++k) {
                        u32 tt = ch[c][k] ^ 0x7FC07FC0u;
                        a |= ((tt - 0x00010001u) & ~tt);
                    }
                }
                if (!__any((a & 0x80008000u) != 0u)) break;
                if (++g > 2000000) break;   // fail-safe: fails LOUDLY (NaN out)
            }
        }

        // ---- stage to wave-private LDS (XOR swizzle: involution both sides) ----
#pragma unroll
        for (int j = 0; j < 8; ++j)
            *(u32x4*)(wbase + j * 1024 + ((lane * 16) ^ (j << 4))) = ch[j];

        // ---- A-fragments from LDS: row bA, u16-col quad*8 + ks*32 ----
        short8 afr[16];
        {
            const char* rb = wbase + bA * 1024;
#pragma unroll
            for (int ks = 0; ks < 16; ++ks)
                afr[ks] = *(const short8*)(rb + ((quad * 16 + ks * 64) ^ (bA << 4)));
        }

        floatx4 p = px, q = qx;
#pragma unroll
        for (int ks = 0; ks < 16; ks += 2) {
            p = __builtin_amdgcn_mfma_f32_16x16x32_bf16(afr[ks],     bfr[ks],     p, 0, 0, 0);
            q = __builtin_amdgcn_mfma_f32_16x16x32_bf16(afr[ks + 1], bfr[ks + 1], q, 0, 0, 0);
        }
        floatx4 acc = p + q;

        // C/D: row = quad*4+r (rows 0..7 real), col = l16 -> wave-private sG
        if (quad < 2) {
            float* gp = sG + wv * 136 + (quad * 4) * 17 + l16;
#pragma unroll
            for (int r = 0; r < 4; ++r) gp[r * 17] = acc[r];
        }
        asm volatile("s_waitcnt lgkmcnt(0)" ::: "memory");

        // gate math: 32 lanes x 1 output (same-wave LDS relay, no barrier)
        float h;
        {
            const float* gr = sG + wv * 136 + gb * 17;
            float gi = gr[gj]      + bi;
            float gJ = gr[4 + gj]  + bj;
            float gF = gr[8 + gj]  + bf;
            float gO = gr[12 + gj] + bo;
            cst = sigf(gF) * cst + sigf(gi) * tanh_(gJ);
            h = sigf(gO) * tanh_(cst);
        }
        // pair lanes (gj even | odd) -> one u32 store per 2 cols
        float hn = __shfl_xor(h, 1, 64);
        if (lane < 32 && (gj & 1) == 0) {
            u32 pk = ((u32)f2bf(hn) << 16) | (u32)f2bf(h);
            *(u32*)(hs + ((size_t)(t + 1) * 64 + b0 + gb) * H_ + s * 16 + wv * 4 + gj) = pk;
        }

#pragma unroll
        for (int ks = 0; ks < 4; ++ks) xcur[ks] = xnxt[ks];
    }
}

// decoder + loss: rows R = t*64+b of hs[1..512]; 32 rows/block staged in LDS
__global__ __launch_bounds__(256) void k_dec(const u16* __restrict__ hs, const float* __restrict__ Wd,
                                             const float* __restrict__ bd, const float* __restrict__ Y,
                                             float* __restrict__ out) {
    __shared__ u16 sH[32 * H_];
    __shared__ float red[4];
    int tid = threadIdx.x;
    int R0 = blockIdx.x * 32;
    for (int u = tid; u < 2048; u += 256) {
        int row = u >> 6, ch = u & 63;
        *(short8*)(sH + row * H_ + ch * 8) =
            *(const short8*)(hs + (size_t)(64 + R0 + row) * H_ + ch * 8);
    }
    __syncthreads();

    int n = tid & 127, half = tid >> 7;
    float bdv = bd[n];
    float acc[16];
#pragma unroll
    for (int i = 0; i < 16; ++i) acc[i] = 0.f;

    for (int ko = 0; ko < H_ / 8; ++ko) {
        float wv[8];
#pragma unroll
        for (int j = 0; j < 8; ++j) wv[j] = Wd[(ko * 8 + j) * N_ + n];
#pragma unroll
        for (int i = 0; i < 16; ++i) {
            int r = half * 16 + i;
            const uint4 hv = *(const uint4*)(sH + r * H_ + ko * 8);
            acc[i] += __uint_as_float(hv.x << 16) * wv[0] + __uint_as_float(hv.x & 0xFFFF0000u) * wv[1]
                    + __uint_as_float(hv.y << 16) * wv[2] + __uint_as_float(hv.y & 0xFFFF0000u) * wv[3]
                    + __uint_as_float(hv.z << 16) * wv[4] + __uint_as_float(hv.z & 0xFFFF0000u) * wv[5]
                    + __uint_as_float(hv.w << 16) * wv[6] + __uint_as_float(hv.w & 0xFFFF0000u) * wv[7];
        }
    }
    float sse = 0.f;
#pragma unroll
    for (int i = 0; i < 16; ++i) {
        int R = R0 + half * 16 + i;
        int t = R >> 6, b = R & 63;
        float logit = sigf(acc[i] + bdv);
        float d = Y[(size_t)(b * T_ + t) * N_ + n] - logit;
        sse += d * d;
    }
    for (int off = 32; off > 0; off >>= 1) sse += __shfl_down(sse, off, 64);
    if ((tid & 63) == 0) red[tid >> 6] = sse;
    __syncthreads();
    if (tid == 0) {
        float tot = red[0] + red[1] + red[2] + red[3];
        atomicAdd(out, tot * (100.0f / 4194304.0f));
    }
}

extern "C" void kernel_launch(void* const* d_in, const int* in_sizes, int n_in,
                              void* d_out, int out_size, void* d_ws, size_t ws_size,
                              hipStream_t stream) {
    (void)in_sizes; (void)n_in; (void)out_size;
    const float* X  = (const float*)d_in[0];
    const float* Y  = (const float*)d_in[1];
    const float* Wx = (const float*)d_in[2];
    const float* Wh = (const float*)d_in[3];
    const float* bb = (const float*)d_in[4];
    const float* Wd = (const float*)d_in[5];
    const float* bd = (const float*)d_in[6];

    char* ws = (char*)d_ws;
    u32* syncz = (u32*)ws;
    const size_t sync_bytes = 131072;
    u16* hs  = (u16*)(ws + sync_bytes);
    const size_t hs_bytes = (size_t)(T_ + 1) * 64 * H_ * 2;   // 33,619,968
    u16* Xb  = (u16*)(ws + sync_bytes + hs_bytes);
    const size_t xb_bytes = (size_t)T_ * 64 * N_ * 2;         // 8,388,608
    u16* Wt  = (u16*)(ws + sync_bytes + hs_bytes + xb_bytes);
    const size_t need = sync_bytes + hs_bytes + xb_bytes + (size_t)2048 * KDIM * 2;
    if (ws_size < need) return;   // ~44.8 MB scratch required

    (void)hipMemsetAsync(syncz, 0, 65536, stream);            // org counters
    (void)hipMemsetAsync(hs, 0, 64 * H_ * 2, stream);         // h_{-1} = 0 (t=0 rows, NOT NaN)
    (void)hipMemsetAsync(d_out, 0, sizeof(float), stream);

    // NaN-sentinel prefill of hs rows [64, 513*64): 2,097,152 uint4 = 33.5 MB
    k_fill<<<dim3(8192), dim3(256), 0, stream>>>((uint4*)(hs + (size_t)64 * H_));

    k_xb<<<dim3((B_ * T_ * N_) / 256), dim3(256), 0, stream>>>(X, Xb);
    k_wcat<<<dim3((2048 * KDIM) / 256), dim3(256), 0, stream>>>(Wx, Wh, Wt);

    void* args[] = { (void*)&Wt, (void*)&Xb, (void*)&hs, (void*)&bb, (void*)&syncz };
    (void)hipLaunchCooperativeKernel((const void*)k_lstm, dim3(256), dim3(256), args, 0, stream);

    k_dec<<<dim3((B_ * T_) / 32), dim3(256), 0, stream>>>(hs, Wd, bd, Y, (float*)d_out);
}